// Round 8
// baseline (1065.163 us; speedup 1.0000x reference)
//
#include <hip/hip_runtime.h>
#include <hip/hip_bf16.h>

#define N_NODES 100000
#define N_EDGES 1600000
#define E_SL (N_EDGES + N_NODES)
#define HID 64
#define NUM_GRAPHS 64
#define NEG_SLOPE 0.2f
#define SCAN_CHUNK 1024
#define SCAN_NB ((N_NODES + SCAN_CHUNK - 1) / SCAN_CHUNK)
#define EA_STRIDE 12   // [ea0..ea7, src_bits, pad, pad, pad] = 48B
#define XP_NODES_PER_BLK 16

// ============ CSR build (once per call, reused by all 3 layers) ============

__global__ void hist_kernel(const int* __restrict__ ei, int* __restrict__ cnt) {
    int e = blockIdx.x * blockDim.x + threadIdx.x;
    if (e >= N_EDGES) return;
    atomicAdd(&cnt[ei[N_EDGES + e]], 1);
}

__global__ void scan_local_kernel(const int* __restrict__ cnt, int* __restrict__ row_ptr,
                                  int* __restrict__ bsum) {
    __shared__ int s[256];
    int t = threadIdx.x;
    int base = blockIdx.x * SCAN_CHUNK + t * 4;
    int v[4]; int sum = 0;
    #pragma unroll
    for (int i = 0; i < 4; ++i) {
        int idx = base + i;
        v[i] = (idx < N_NODES) ? cnt[idx] + 1 : 0;
        sum += v[i];
    }
    s[t] = sum;
    __syncthreads();
    for (int off = 1; off < 256; off <<= 1) {
        int x = (t >= off) ? s[t - off] : 0;
        __syncthreads();
        s[t] += x;
        __syncthreads();
    }
    int run = s[t] - sum;
    #pragma unroll
    for (int i = 0; i < 4; ++i) {
        int idx = base + i;
        if (idx < N_NODES) row_ptr[idx] = run;
        run += v[i];
    }
    if (t == 255) bsum[blockIdx.x] = s[255];
}

__global__ void scan_bsum_kernel(int* __restrict__ bsum) {
    if (threadIdx.x != 0) return;
    int acc = 0;
    for (int i = 0; i < SCAN_NB; ++i) { int v = bsum[i]; bsum[i] = acc; acc += v; }
}

__global__ void scan_add_kernel(int* __restrict__ row_ptr, const int* __restrict__ bsum) {
    int i = blockIdx.x * blockDim.x + threadIdx.x;
    if (i > N_NODES) return;
    if (i == N_NODES) row_ptr[i] = E_SL;
    else row_ptr[i] += bsum[i >> 10];
}

// Fused scatter+permute: 8 lanes per edge; lane j==0 claims the CSR slot,
// broadcasts pos; lanes write ea (coalesced read) + src to final slot.
__global__ void build_csr_kernel(const int* __restrict__ ei, const float* __restrict__ ea,
                                 const int* __restrict__ row_ptr, int* __restrict__ cursor,
                                 float* __restrict__ ea_csr) {
    long long idx = (long long)blockIdx.x * blockDim.x + threadIdx.x;
    if (idx >= (long long)N_EDGES * 8) return;
    int e = (int)(idx >> 3), j = (int)(idx & 7);
    int lane = threadIdx.x & 63;
    int pos = 0;
    if (j == 0) {
        int d = ei[N_EDGES + e];
        pos = row_ptr[d] + atomicAdd(&cursor[d], 1);
    }
    pos = __shfl(pos, lane & ~7);
    size_t base = (size_t)pos * EA_STRIDE;
    ea_csr[base + j] = ea[idx];
    if (j == 0) ((int*)ea_csr)[base + 8] = ei[e];
}

// self-loop row (last slot per segment) = mean of real incoming attrs + src=n.
// 2 threads/node, float4 reads (4x fewer load instrs than 8-scalar version).
__global__ void mean_ea_kernel(const int* __restrict__ row_ptr, float* __restrict__ ea_csr) {
    int idx = blockIdx.x * blockDim.x + threadIdx.x;
    if (idx >= N_NODES * 2) return;
    int n = idx >> 1, jj = (idx & 1) * 4;
    int start = row_ptr[n], last = row_ptr[n + 1] - 1;
    float4 s = make_float4(0.f, 0.f, 0.f, 0.f);
    for (int pos = start; pos < last; ++pos) {
        float4 v = *(const float4*)(ea_csr + (size_t)pos * EA_STRIDE + jj);
        s.x += v.x; s.y += v.y; s.z += v.z; s.w += v.w;
    }
    float invd = 1.f / fmaxf((float)(last - start), 1.f);
    s.x *= invd; s.y *= invd; s.z *= invd; s.w *= invd;
    *(float4*)(ea_csr + (size_t)last * EA_STRIDE + jj) = s;
    if (jj == 0) ((int*)ea_csr)[(size_t)last * EA_STRIDE + 8] = n;
}

// ============ per-layer kernels ============

__global__ void weff_all_kernel(const float* __restrict__ We0, const float* __restrict__ ae0,
                                const float* __restrict__ Weh, const float* __restrict__ aeh,
                                float* __restrict__ weff) {
    int t = threadIdx.x;
    if (t >= 96) return;
    int layer = t >> 5, r = t & 31;
    int dd = r >> 2, h = r & 3;
    const float* We = (layer == 0) ? We0 : Weh + (size_t)(layer - 1) * 8 * 64;
    const float* ae = (layer == 0) ? ae0 : aeh + (size_t)(layer - 1) * 64;
    float s = 0.f;
    #pragma unroll
    for (int c = 0; c < 16; ++c) s += We[dd * 64 + h * 16 + c] * ae[h * 16 + c];
    weff[layer * 32 + dd * 4 + h] = s;
}

// xp = x @ W ; als/ald per-node logits.
// v2: ONE wave per block; W column held in VGPRs (preloaded once, amortized over
// 16 nodes); x-row addresses are wave-uniform (no threadIdx) -> s_load path;
// 4 independent accumulators for ILP. Replaces the LDS-issue-bound v1
// (~370 cyc/node: one ds_read_b32 per FMA).
template <int FIN>
__global__ __launch_bounds__(64) void xp_kernel(
    const float* __restrict__ xin, const float* __restrict__ W,
    const float* __restrict__ a_s, const float* __restrict__ a_d,
    float* __restrict__ xp, float* __restrict__ als, float* __restrict__ ald) {
    int lane = threadIdx.x;
    float wcol[FIN];
    #pragma unroll
    for (int k = 0; k < FIN; ++k) wcol[k] = W[k * 64 + lane];   // coalesced 256B per k
    float asl = a_s[lane], adl = a_d[lane];
    int n0 = blockIdx.x * XP_NODES_PER_BLK;
    #pragma unroll 1
    for (int ni = 0; ni < XP_NODES_PER_BLK; ++ni) {
        int n = n0 + ni;
        if (n >= N_NODES) return;
        const float* xr = xin + (size_t)n * FIN;   // wave-uniform address
        float a0 = 0.f, a1 = 0.f, a2 = 0.f, a3 = 0.f;
        #pragma unroll
        for (int k = 0; k < FIN; k += 4) {
            float4 xv = *(const float4*)(xr + k);
            a0 += xv.x * wcol[k];     a1 += xv.y * wcol[k + 1];
            a2 += xv.z * wcol[k + 2]; a3 += xv.w * wcol[k + 3];
        }
        float acc = (a0 + a1) + (a2 + a3);
        xp[(size_t)n * 64 + lane] = acc;
        float ps = acc * asl, pd = acc * adl;
        #pragma unroll
        for (int mk = 8; mk >= 1; mk >>= 1) {
            ps += __shfl_xor(ps, mk, 16);
            pd += __shfl_xor(pd, mk, 16);
        }
        if ((lane & 15) == 0) {
            als[(size_t)n * 4 + (lane >> 4)] = ps;
            ald[(size_t)n * 4 + (lane >> 4)] = pd;
        }
    }
}

__device__ __forceinline__ float pick4(float a, float b, float c, float d, int h) {
    float ab = (h & 1) ? b : a;
    float cd = (h & 1) ? d : c;
    return (h & 2) ? cd : ab;
}

// Fused GAT with ONLINE softmax: one wave per node.
// Phases 1-2: lane = edge within 64-wide chunk (logits/max/exp).
// Phase 3: lane = (column-quad cq, edge-subgroup eg); float4 row gathers with
// 8 loads in flight; the softmax DENOMINATOR is accumulated here too (csum),
// deleting the per-chunk denominator shuffle tree of the previous version.
__global__ __launch_bounds__(256) void gat_node_kernel(
    const int* __restrict__ row_ptr, const float* __restrict__ ea_csr,
    const float* __restrict__ als, const float* __restrict__ ald,
    const float* __restrict__ weff, const float* __restrict__ xp,
    float* __restrict__ out, const float* __restrict__ bias, int relu_flag) {
    __shared__ float exl[4 * 256];   // per-wave: 64 edges x 4 heads
    int wave = threadIdx.x >> 6, lane = threadIdx.x & 63;
    int node = blockIdx.x * 4 + wave;
    if (node >= N_NODES) return;
    int start = row_ptr[node], end = row_ptr[node + 1];
    int deg = end - start;                       // >= 1 (self-loop)
    int wb4 = wave * 256;
    int cq = lane & 15;                          // column quad: cols 4cq..4cq+3
    int eg = lane >> 4;                          // edge subgroup 0..3
    int hv = cq >> 2;                            // head for this column quad

    float4 w0 = *(const float4*)(weff + 0),  w1 = *(const float4*)(weff + 4);
    float4 w2 = *(const float4*)(weff + 8),  w3 = *(const float4*)(weff + 12);
    float4 w4 = *(const float4*)(weff + 16), w5 = *(const float4*)(weff + 20);
    float4 w6 = *(const float4*)(weff + 24), w7 = *(const float4*)(weff + 28);
    float4 ad4 = *(const float4*)(ald + (size_t)node * 4);

    float m[4] = {-1e30f, -1e30f, -1e30f, -1e30f};
    float4 acc4 = make_float4(0.f, 0.f, 0.f, 0.f);
    float csum = 0.f;                            // per-head coefficient sum (denominator)

    for (int base = 0; base < deg; base += 64) {
        int cnt = min(64, deg - base);
        float lg[4] = {-1e30f, -1e30f, -1e30f, -1e30f};
        if (lane < cnt) {
            const float* row = ea_csr + (size_t)(start + base + lane) * EA_STRIDE;
            float4 a0 = *(const float4*)row;
            float4 a1 = *(const float4*)(row + 4);
            int s = ((const int*)row)[8];
            float4 as4 = *(const float4*)(als + (size_t)s * 4);
            #pragma unroll
            for (int h = 0; h < 4; ++h) {
                float ale = a0.x * pick4(w0.x, w0.y, w0.z, w0.w, h)
                          + a0.y * pick4(w1.x, w1.y, w1.z, w1.w, h)
                          + a0.z * pick4(w2.x, w2.y, w2.z, w2.w, h)
                          + a0.w * pick4(w3.x, w3.y, w3.z, w3.w, h)
                          + a1.x * pick4(w4.x, w4.y, w4.z, w4.w, h)
                          + a1.y * pick4(w5.x, w5.y, w5.z, w5.w, h)
                          + a1.z * pick4(w6.x, w6.y, w6.z, w6.w, h)
                          + a1.w * pick4(w7.x, w7.y, w7.z, w7.w, h);
                float v = pick4(as4.x, as4.y, as4.z, as4.w, h)
                        + pick4(ad4.x, ad4.y, ad4.z, ad4.w, h) + ale;
                lg[h] = (v >= 0.f) ? v : NEG_SLOPE * v;
            }
        }
        // chunk max per head -> running max + rescale
        float cm[4] = {lg[0], lg[1], lg[2], lg[3]};
        #pragma unroll
        for (int mk = 1; mk < 64; mk <<= 1) {
            #pragma unroll
            for (int h = 0; h < 4; ++h) cm[h] = fmaxf(cm[h], __shfl_xor(cm[h], mk));
        }
        float scale[4], ex[4];
        #pragma unroll
        for (int h = 0; h < 4; ++h) {
            float mn = fmaxf(m[h], cm[h]);
            scale[h] = expf(m[h] - mn);   // first chunk: exp(-inf)=0, benign
            m[h] = mn;
            ex[h] = (lane < cnt) ? expf(lg[h] - mn) : 0.f;
        }
        // stage coefficients in LDS (per-wave region, wave-synchronous)
        *(float4*)(exl + wb4 + lane * 4) = make_float4(ex[0], ex[1], ex[2], ex[3]);
        // ---- phase 3: subgroup eg handles edges j = eg, eg+4, ...; also sums coeffs ----
        float4 acc2 = make_float4(0.f, 0.f, 0.f, 0.f);
        float cs2 = 0.f;
        const float* exw = exl + wb4 + hv;
        const int* srcw = (const int*)ea_csr + 8;   // src at word 8 of each row
        size_t rowbase = (size_t)(start + base) * EA_STRIDE;
        int j = eg;
        for (; j + 28 < cnt; j += 32) {
            float c[8]; float4 xv[8];
            #pragma unroll
            for (int u = 0; u < 8; ++u) {
                int jj = j + u * 4;
                int sj = srcw[rowbase + (size_t)jj * EA_STRIDE];
                c[u] = exw[jj * 4];
                xv[u] = *(const float4*)(xp + (size_t)sj * 64 + cq * 4);
            }
            #pragma unroll
            for (int u = 0; u < 8; ++u) {
                acc2.x += c[u] * xv[u].x; acc2.y += c[u] * xv[u].y;
                acc2.z += c[u] * xv[u].z; acc2.w += c[u] * xv[u].w;
                cs2 += c[u];
            }
        }
        for (; j < cnt; j += 4) {
            int sj = srcw[rowbase + (size_t)j * EA_STRIDE];
            float cj = exw[j * 4];
            float4 xv = *(const float4*)(xp + (size_t)sj * 64 + cq * 4);
            acc2.x += cj * xv.x; acc2.y += cj * xv.y;
            acc2.z += cj * xv.z; acc2.w += cj * xv.w;
            cs2 += cj;
        }
        float sc = scale[hv];
        acc4.x = acc4.x * sc + acc2.x;
        acc4.y = acc4.y * sc + acc2.y;
        acc4.z = acc4.z * sc + acc2.z;
        acc4.w = acc4.w * sc + acc2.w;
        csum   = csum   * sc + cs2;
    }
    // reduce across the 4 edge-subgroups (lanes cq, cq+16, cq+32, cq+48)
    #pragma unroll
    for (int mk = 16; mk < 64; mk <<= 1) {
        acc4.x += __shfl_xor(acc4.x, mk);
        acc4.y += __shfl_xor(acc4.y, mk);
        acc4.z += __shfl_xor(acc4.z, mk);
        acc4.w += __shfl_xor(acc4.w, mk);
        csum   += __shfl_xor(csum, mk);
    }
    if (eg == 0) {
        float inv = 1.f / (csum + 1e-16f);
        float4 b4 = *(const float4*)(bias + cq * 4);
        float4 v;
        v.x = acc4.x * inv + b4.x;
        v.y = acc4.y * inv + b4.y;
        v.z = acc4.z * inv + b4.z;
        v.w = acc4.w * inv + b4.w;
        if (relu_flag) {
            v.x = fmaxf(v.x, 0.f); v.y = fmaxf(v.y, 0.f);
            v.z = fmaxf(v.z, 0.f); v.w = fmaxf(v.w, 0.f);
        }
        *(float4*)(out + (size_t)node * 64 + cq * 4) = v;
    }
}

// ---- graph mean pool: one block per graph; batch sorted -> binary-search bounds ----
__global__ void pool_kernel(const float* __restrict__ h, const int* __restrict__ batch,
                            float* __restrict__ pooled) {
    int g = blockIdx.x;
    int lo = 0, hi = N_NODES;
    while (lo < hi) { int mid = (lo + hi) >> 1; if (batch[mid] < g) lo = mid + 1; else hi = mid; }
    int start = lo;
    hi = N_NODES;
    while (lo < hi) { int mid = (lo + hi) >> 1; if (batch[mid] < g + 1) lo = mid + 1; else hi = mid; }
    int end = lo;
    int tid = threadIdx.x;
    int c = tid & 63, r = tid >> 6;
    float acc = 0.f;
    for (int n = start + r; n < end; n += 4) acc += h[(size_t)n * 64 + c];
    __shared__ float red[256];
    red[tid] = acc;
    __syncthreads();
    if (tid < 64) {
        float s = red[tid] + red[tid + 64] + red[tid + 128] + red[tid + 192];
        float cg = fmaxf((float)(end - start), 1.0f);
        pooled[g * 64 + tid] = s / cg;
    }
}

__global__ void mlp_kernel(const float* __restrict__ pooled,
                           const float* __restrict__ w1, const float* __restrict__ b1,
                           const float* __restrict__ w2, const float* __restrict__ b2,
                           float* __restrict__ y) {
    int g = blockIdx.x, t = threadIdx.x;
    __shared__ float p[64], f1[32];
    p[t] = pooled[g * 64 + t];
    __syncthreads();
    if (t < 32) {
        float a = b1[t];
        #pragma unroll
        for (int k = 0; k < 64; ++k) a += p[k] * w1[k * 32 + t];
        f1[t] = fmaxf(a, 0.f);
    }
    __syncthreads();
    if (t < 2) {
        float a = b2[t];
        #pragma unroll
        for (int k = 0; k < 32; ++k) a += f1[k] * w2[k * 2 + t];
        y[g * 2 + t] = a;
    }
}

extern "C" void kernel_launch(void* const* d_in, const int* in_sizes, int n_in,
                              void* d_out, int out_size, void* d_ws, size_t ws_size,
                              hipStream_t stream) {
    const float* x    = (const float*)d_in[0];
    const int*   ei   = (const int*)d_in[1];
    const float* ea   = (const float*)d_in[2];
    const int*   batch= (const int*)d_in[3];
    const float* W0   = (const float*)d_in[4];
    const float* as0  = (const float*)d_in[5];
    const float* ad0  = (const float*)d_in[6];
    const float* We0  = (const float*)d_in[7];
    const float* ae0  = (const float*)d_in[8];
    const float* b0   = (const float*)d_in[9];
    const float* Wh   = (const float*)d_in[10];
    const float* ash  = (const float*)d_in[11];
    const float* adh  = (const float*)d_in[12];
    const float* Weh  = (const float*)d_in[13];
    const float* aeh  = (const float*)d_in[14];
    const float* bh   = (const float*)d_in[15];
    const float* w1   = (const float*)d_in[16];
    const float* b1   = (const float*)d_in[17];
    const float* w2   = (const float*)d_in[18];
    const float* b2   = (const float*)d_in[19];
    float* out = (float*)d_out;

    char* wsb = (char*)d_ws;
    size_t off = 0;
    auto alloc = [&](size_t bytes) { char* p = wsb + off; off += (bytes + 255) & ~(size_t)255; return p; };
    int*   row_ptr = (int*)alloc((size_t)(N_NODES + 1) * 4);
    float* ea_csr  = (float*)alloc((size_t)E_SL * EA_STRIDE * 4);
    float* als     = (float*)alloc((size_t)N_NODES * 4 * 4);
    float* ald     = (float*)alloc((size_t)N_NODES * 4 * 4);
    float* weff    = (float*)alloc(3 * 32 * 4);
    float* pooled  = (float*)alloc((size_t)NUM_GRAPHS * 64 * 4);
    float* bufA    = (float*)alloc((size_t)N_NODES * 64 * 4);  // xp
    float* bufB    = (float*)alloc((size_t)N_NODES * 64 * 4);  // h (layer output)
    // CSR-build scratch ALIASED into bufA (dead before xp_kernel writes bufA)
    int* cnt    = (int*)bufA;
    int* cursor = cnt + N_NODES;     // contiguous with cnt -> single memset
    int* bsum   = cursor + N_NODES;

    // ---- CSR build (once) ----
    hipMemsetAsync(cnt, 0, (size_t)2 * N_NODES * 4, stream);   // cnt + cursor
    hist_kernel<<<(N_EDGES + 255) / 256, 256, 0, stream>>>(ei, cnt);
    scan_local_kernel<<<SCAN_NB, 256, 0, stream>>>(cnt, row_ptr, bsum);
    scan_bsum_kernel<<<1, 64, 0, stream>>>(bsum);
    scan_add_kernel<<<(N_NODES + 256) / 256, 256, 0, stream>>>(row_ptr, bsum);
    build_csr_kernel<<<(int)(((long long)N_EDGES * 8 + 255) / 256), 256, 0, stream>>>(
        ei, ea, row_ptr, cursor, ea_csr);
    mean_ea_kernel<<<(N_NODES * 2 + 255) / 256, 256, 0, stream>>>(row_ptr, ea_csr);
    weff_all_kernel<<<1, 128, 0, stream>>>(We0, ae0, Weh, aeh, weff);

    // ---- 3 GAT layers (xin -> bufA(xp) -> bufB(h); bufB feeds next layer) ----
    for (int layer = 0; layer < 3; ++layer) {
        const float *W, *as_, *ad_, *bb, *xin;
        int relu_flag = (layer == 0);
        if (layer == 0) {
            W = W0; as_ = as0; ad_ = ad0; bb = b0; xin = x;
        } else {
            int i = layer - 1;
            W   = Wh  + (size_t)i * 64 * 64;
            as_ = ash + (size_t)i * 64;
            ad_ = adh + (size_t)i * 64;
            bb  = bh  + (size_t)i * 64;
            xin = bufB;
        }
        int xpgrid = (N_NODES + XP_NODES_PER_BLK - 1) / XP_NODES_PER_BLK;
        if (layer == 0)
            xp_kernel<32><<<xpgrid, 64, 0, stream>>>(xin, W, as_, ad_, bufA, als, ald);
        else
            xp_kernel<64><<<xpgrid, 64, 0, stream>>>(xin, W, as_, ad_, bufA, als, ald);
        gat_node_kernel<<<(N_NODES + 3) / 4, 256, 0, stream>>>(
            row_ptr, ea_csr, als, ald, weff + layer * 32, bufA, bufB, bb, relu_flag);
    }
    pool_kernel<<<NUM_GRAPHS, 256, 0, stream>>>(bufB, batch, pooled);
    mlp_kernel<<<NUM_GRAPHS, 64, 0, stream>>>(pooled, w1, b1, w2, b2, out);
}

// Round 9
// 857.448 us; speedup vs baseline: 1.2422x; 1.2422x over previous
//
#include <hip/hip_runtime.h>
#include <hip/hip_bf16.h>
#include <hip/hip_fp16.h>

#define N_NODES 100000
#define N_EDGES 1600000
#define E_SL (N_EDGES + N_NODES)
#define HID 64
#define NUM_GRAPHS 64
#define NEG_SLOPE 0.2f
#define SCAN_CHUNK 1024
#define SCAN_NB ((N_NODES + SCAN_CHUNK - 1) / SCAN_CHUNK)
#define EA_STRIDE 12   // [ea0..ea7, src_bits, pad, pad, pad] = 48B
#define XP_NODES_PER_BLK 16

// ============ CSR build (once per call, reused by all 3 layers) ============

__global__ void hist_kernel(const int* __restrict__ ei, int* __restrict__ cnt) {
    int e = blockIdx.x * blockDim.x + threadIdx.x;
    if (e >= N_EDGES) return;
    atomicAdd(&cnt[ei[N_EDGES + e]], 1);
}

__global__ void scan_local_kernel(const int* __restrict__ cnt, int* __restrict__ row_ptr,
                                  int* __restrict__ bsum) {
    __shared__ int s[256];
    int t = threadIdx.x;
    int base = blockIdx.x * SCAN_CHUNK + t * 4;
    int v[4]; int sum = 0;
    #pragma unroll
    for (int i = 0; i < 4; ++i) {
        int idx = base + i;
        v[i] = (idx < N_NODES) ? cnt[idx] + 1 : 0;
        sum += v[i];
    }
    s[t] = sum;
    __syncthreads();
    for (int off = 1; off < 256; off <<= 1) {
        int x = (t >= off) ? s[t - off] : 0;
        __syncthreads();
        s[t] += x;
        __syncthreads();
    }
    int run = s[t] - sum;
    #pragma unroll
    for (int i = 0; i < 4; ++i) {
        int idx = base + i;
        if (idx < N_NODES) row_ptr[idx] = run;
        run += v[i];
    }
    if (t == 255) bsum[blockIdx.x] = s[255];
}

__global__ void scan_bsum_kernel(int* __restrict__ bsum) {
    if (threadIdx.x != 0) return;
    int acc = 0;
    for (int i = 0; i < SCAN_NB; ++i) { int v = bsum[i]; bsum[i] = acc; acc += v; }
}

__global__ void scan_add_kernel(int* __restrict__ row_ptr, const int* __restrict__ bsum) {
    int i = blockIdx.x * blockDim.x + threadIdx.x;
    if (i > N_NODES) return;
    if (i == N_NODES) row_ptr[i] = E_SL;
    else row_ptr[i] += bsum[i >> 10];
}

// Fused scatter+permute: 8 lanes per edge; lane j==0 claims the CSR slot,
// broadcasts pos; lanes write ea (coalesced read) + src to final slot.
__global__ void build_csr_kernel(const int* __restrict__ ei, const float* __restrict__ ea,
                                 const int* __restrict__ row_ptr, int* __restrict__ cursor,
                                 float* __restrict__ ea_csr) {
    long long idx = (long long)blockIdx.x * blockDim.x + threadIdx.x;
    if (idx >= (long long)N_EDGES * 8) return;
    int e = (int)(idx >> 3), j = (int)(idx & 7);
    int lane = threadIdx.x & 63;
    int pos = 0;
    if (j == 0) {
        int d = ei[N_EDGES + e];
        pos = row_ptr[d] + atomicAdd(&cursor[d], 1);
    }
    pos = __shfl(pos, lane & ~7);
    size_t base = (size_t)pos * EA_STRIDE;
    ea_csr[base + j] = ea[idx];
    if (j == 0) ((int*)ea_csr)[base + 8] = ei[e];
}

// self-loop row (last slot per segment) = mean of real incoming attrs + src=n.
__global__ void mean_ea_kernel(const int* __restrict__ row_ptr, float* __restrict__ ea_csr) {
    int idx = blockIdx.x * blockDim.x + threadIdx.x;
    if (idx >= N_NODES * 2) return;
    int n = idx >> 1, jj = (idx & 1) * 4;
    int start = row_ptr[n], last = row_ptr[n + 1] - 1;
    float4 s = make_float4(0.f, 0.f, 0.f, 0.f);
    for (int pos = start; pos < last; ++pos) {
        float4 v = *(const float4*)(ea_csr + (size_t)pos * EA_STRIDE + jj);
        s.x += v.x; s.y += v.y; s.z += v.z; s.w += v.w;
    }
    float invd = 1.f / fmaxf((float)(last - start), 1.f);
    s.x *= invd; s.y *= invd; s.z *= invd; s.w *= invd;
    *(float4*)(ea_csr + (size_t)last * EA_STRIDE + jj) = s;
    if (jj == 0) ((int*)ea_csr)[(size_t)last * EA_STRIDE + 8] = n;
}

// ============ per-layer kernels ============

__global__ void weff_all_kernel(const float* __restrict__ We0, const float* __restrict__ ae0,
                                const float* __restrict__ Weh, const float* __restrict__ aeh,
                                float* __restrict__ weff) {
    int t = threadIdx.x;
    if (t >= 96) return;
    int layer = t >> 5, r = t & 31;
    int dd = r >> 2, h = r & 3;
    const float* We = (layer == 0) ? We0 : Weh + (size_t)(layer - 1) * 8 * 64;
    const float* ae = (layer == 0) ? ae0 : aeh + (size_t)(layer - 1) * 64;
    float s = 0.f;
    #pragma unroll
    for (int c = 0; c < 16; ++c) s += We[dd * 64 + h * 16 + c] * ae[h * 16 + c];
    weff[layer * 32 + dd * 4 + h] = s;
}

// xp = x @ W (output stored FP16 -> halves gather bytes in gat_node);
// als/ald per-node logits in fp32. One wave per block; W column in VGPRs,
// wave-uniform x-row loads (s_load path), 4 independent accumulators.
template <int FIN>
__global__ __launch_bounds__(64) void xp_kernel(
    const float* __restrict__ xin, const float* __restrict__ W,
    const float* __restrict__ a_s, const float* __restrict__ a_d,
    __half* __restrict__ xp, float* __restrict__ als, float* __restrict__ ald) {
    int lane = threadIdx.x;
    float wcol[FIN];
    #pragma unroll
    for (int k = 0; k < FIN; ++k) wcol[k] = W[k * 64 + lane];   // coalesced 256B per k
    float asl = a_s[lane], adl = a_d[lane];
    int n0 = blockIdx.x * XP_NODES_PER_BLK;
    #pragma unroll 1
    for (int ni = 0; ni < XP_NODES_PER_BLK; ++ni) {
        int n = n0 + ni;
        if (n >= N_NODES) return;
        const float* xr = xin + (size_t)n * FIN;   // wave-uniform address
        float a0 = 0.f, a1 = 0.f, a2 = 0.f, a3 = 0.f;
        #pragma unroll
        for (int k = 0; k < FIN; k += 4) {
            float4 xv = *(const float4*)(xr + k);
            a0 += xv.x * wcol[k];     a1 += xv.y * wcol[k + 1];
            a2 += xv.z * wcol[k + 2]; a3 += xv.w * wcol[k + 3];
        }
        float acc = (a0 + a1) + (a2 + a3);
        xp[(size_t)n * 64 + lane] = __float2half(acc);
        float ps = acc * asl, pd = acc * adl;
        #pragma unroll
        for (int mk = 8; mk >= 1; mk >>= 1) {
            ps += __shfl_xor(ps, mk, 16);
            pd += __shfl_xor(pd, mk, 16);
        }
        if ((lane & 15) == 0) {
            als[(size_t)n * 4 + (lane >> 4)] = ps;
            ald[(size_t)n * 4 + (lane >> 4)] = pd;
        }
    }
}

__device__ __forceinline__ float pick4(float a, float b, float c, float d, int h) {
    float ab = (h & 1) ? b : a;
    float cd = (h & 1) ? d : c;
    return (h & 2) ? cd : ab;
}

// Fused GAT with ONLINE softmax: one wave per node.
// Phases 1-2: lane = edge within 64-wide chunk (logits/max/exp); src ids staged
// in LDS coll[] -- CRITICAL: phase-3 gather ADDRESSES must come from LDS
// (lgkmcnt), not global (vmcnt), or the dependent-address chain drains the
// gather queue (R8 regression: 158us vs ~120us). Denominator accumulated in
// phase 3 (csum), no per-chunk shuffle tree.
// Phase 3: lane = (column-quad cq, edge-subgroup eg); fp16 rows -> 8B/lane,
// one gather instruction covers 4 rows (512B), 8 gathers in flight.
__global__ __launch_bounds__(256) void gat_node_kernel(
    const int* __restrict__ row_ptr, const float* __restrict__ ea_csr,
    const float* __restrict__ als, const float* __restrict__ ald,
    const float* __restrict__ weff, const __half* __restrict__ xp,
    float* __restrict__ out, const float* __restrict__ bias, int relu_flag) {
    __shared__ float exl[4 * 256];   // per-wave: 64 edges x 4 heads
    __shared__ int   coll[4 * 64];   // per-wave: 64 src ids
    int wave = threadIdx.x >> 6, lane = threadIdx.x & 63;
    int node = blockIdx.x * 4 + wave;
    if (node >= N_NODES) return;
    int start = row_ptr[node], end = row_ptr[node + 1];
    int deg = end - start;                       // >= 1 (self-loop)
    int wb = wave * 64, wb4 = wave * 256;
    int cq = lane & 15;                          // column quad: cols 4cq..4cq+3
    int eg = lane >> 4;                          // edge subgroup 0..3
    int hv = cq >> 2;                            // head for this column quad

    float4 w0 = *(const float4*)(weff + 0),  w1 = *(const float4*)(weff + 4);
    float4 w2 = *(const float4*)(weff + 8),  w3 = *(const float4*)(weff + 12);
    float4 w4 = *(const float4*)(weff + 16), w5 = *(const float4*)(weff + 20);
    float4 w6 = *(const float4*)(weff + 24), w7 = *(const float4*)(weff + 28);
    float4 ad4 = *(const float4*)(ald + (size_t)node * 4);

    float m[4] = {-1e30f, -1e30f, -1e30f, -1e30f};
    float4 acc4 = make_float4(0.f, 0.f, 0.f, 0.f);
    float csum = 0.f;                            // per-head coefficient sum (denominator)

    for (int base = 0; base < deg; base += 64) {
        int cnt = min(64, deg - base);
        float lg[4] = {-1e30f, -1e30f, -1e30f, -1e30f};
        int s = 0;
        if (lane < cnt) {
            const float* row = ea_csr + (size_t)(start + base + lane) * EA_STRIDE;
            float4 a0 = *(const float4*)row;
            float4 a1 = *(const float4*)(row + 4);
            s = ((const int*)row)[8];
            float4 as4 = *(const float4*)(als + (size_t)s * 4);
            #pragma unroll
            for (int h = 0; h < 4; ++h) {
                float ale = a0.x * pick4(w0.x, w0.y, w0.z, w0.w, h)
                          + a0.y * pick4(w1.x, w1.y, w1.z, w1.w, h)
                          + a0.z * pick4(w2.x, w2.y, w2.z, w2.w, h)
                          + a0.w * pick4(w3.x, w3.y, w3.z, w3.w, h)
                          + a1.x * pick4(w4.x, w4.y, w4.z, w4.w, h)
                          + a1.y * pick4(w5.x, w5.y, w5.z, w5.w, h)
                          + a1.z * pick4(w6.x, w6.y, w6.z, w6.w, h)
                          + a1.w * pick4(w7.x, w7.y, w7.z, w7.w, h);
                float v = pick4(as4.x, as4.y, as4.z, as4.w, h)
                        + pick4(ad4.x, ad4.y, ad4.z, ad4.w, h) + ale;
                lg[h] = (v >= 0.f) ? v : NEG_SLOPE * v;
            }
        }
        // chunk max per head -> running max + rescale
        float cm[4] = {lg[0], lg[1], lg[2], lg[3]};
        #pragma unroll
        for (int mk = 1; mk < 64; mk <<= 1) {
            #pragma unroll
            for (int h = 0; h < 4; ++h) cm[h] = fmaxf(cm[h], __shfl_xor(cm[h], mk));
        }
        float scale[4], ex[4];
        #pragma unroll
        for (int h = 0; h < 4; ++h) {
            float mn = fmaxf(m[h], cm[h]);
            scale[h] = expf(m[h] - mn);   // first chunk: exp(-inf)=0, benign
            m[h] = mn;
            ex[h] = (lane < cnt) ? expf(lg[h] - mn) : 0.f;
        }
        // stage coefficients + src ids in LDS (per-wave region, wave-synchronous)
        *(float4*)(exl + wb4 + lane * 4) = make_float4(ex[0], ex[1], ex[2], ex[3]);
        coll[wb + lane] = s;
        // ---- phase 3: subgroup eg handles edges j = eg, eg+4, ...; sums coeffs too ----
        float4 acc2 = make_float4(0.f, 0.f, 0.f, 0.f);
        float cs2 = 0.f;
        const float* exw = exl + wb4 + hv;
        int j = eg;
        for (; j + 28 < cnt; j += 32) {
            float c[8]; uint2 xv[8];
            #pragma unroll
            for (int u = 0; u < 8; ++u) {
                int jj = j + u * 4;
                int sj = coll[wb + jj];
                c[u] = exw[jj * 4];
                xv[u] = *(const uint2*)(xp + (size_t)sj * 64 + cq * 4);
            }
            #pragma unroll
            for (int u = 0; u < 8; ++u) {
                float2 f0 = __half22float2(*(const __half2*)&xv[u].x);
                float2 f1 = __half22float2(*(const __half2*)&xv[u].y);
                acc2.x += c[u] * f0.x; acc2.y += c[u] * f0.y;
                acc2.z += c[u] * f1.x; acc2.w += c[u] * f1.y;
                cs2 += c[u];
            }
        }
        for (; j < cnt; j += 4) {
            int sj = coll[wb + j];
            float cj = exw[j * 4];
            uint2 xv = *(const uint2*)(xp + (size_t)sj * 64 + cq * 4);
            float2 f0 = __half22float2(*(const __half2*)&xv.x);
            float2 f1 = __half22float2(*(const __half2*)&xv.y);
            acc2.x += cj * f0.x; acc2.y += cj * f0.y;
            acc2.z += cj * f1.x; acc2.w += cj * f1.y;
            cs2 += cj;
        }
        float sc = pick4(scale[0], scale[1], scale[2], scale[3], hv);
        acc4.x = acc4.x * sc + acc2.x;
        acc4.y = acc4.y * sc + acc2.y;
        acc4.z = acc4.z * sc + acc2.z;
        acc4.w = acc4.w * sc + acc2.w;
        csum   = csum   * sc + cs2;
    }
    // reduce across the 4 edge-subgroups (lanes cq, cq+16, cq+32, cq+48)
    #pragma unroll
    for (int mk = 16; mk < 64; mk <<= 1) {
        acc4.x += __shfl_xor(acc4.x, mk);
        acc4.y += __shfl_xor(acc4.y, mk);
        acc4.z += __shfl_xor(acc4.z, mk);
        acc4.w += __shfl_xor(acc4.w, mk);
        csum   += __shfl_xor(csum, mk);
    }
    if (eg == 0) {
        float inv = 1.f / (csum + 1e-16f);
        float4 b4 = *(const float4*)(bias + cq * 4);
        float4 v;
        v.x = acc4.x * inv + b4.x;
        v.y = acc4.y * inv + b4.y;
        v.z = acc4.z * inv + b4.z;
        v.w = acc4.w * inv + b4.w;
        if (relu_flag) {
            v.x = fmaxf(v.x, 0.f); v.y = fmaxf(v.y, 0.f);
            v.z = fmaxf(v.z, 0.f); v.w = fmaxf(v.w, 0.f);
        }
        *(float4*)(out + (size_t)node * 64 + cq * 4) = v;
    }
}

// ---- graph mean pool: one block per graph; batch sorted -> binary-search bounds ----
__global__ void pool_kernel(const float* __restrict__ h, const int* __restrict__ batch,
                            float* __restrict__ pooled) {
    int g = blockIdx.x;
    int lo = 0, hi = N_NODES;
    while (lo < hi) { int mid = (lo + hi) >> 1; if (batch[mid] < g) lo = mid + 1; else hi = mid; }
    int start = lo;
    hi = N_NODES;
    while (lo < hi) { int mid = (lo + hi) >> 1; if (batch[mid] < g + 1) lo = mid + 1; else hi = mid; }
    int end = lo;
    int tid = threadIdx.x;
    int c = tid & 63, r = tid >> 6;
    float acc = 0.f;
    for (int n = start + r; n < end; n += 4) acc += h[(size_t)n * 64 + c];
    __shared__ float red[256];
    red[tid] = acc;
    __syncthreads();
    if (tid < 64) {
        float s = red[tid] + red[tid + 64] + red[tid + 128] + red[tid + 192];
        float cg = fmaxf((float)(end - start), 1.0f);
        pooled[g * 64 + tid] = s / cg;
    }
}

__global__ void mlp_kernel(const float* __restrict__ pooled,
                           const float* __restrict__ w1, const float* __restrict__ b1,
                           const float* __restrict__ w2, const float* __restrict__ b2,
                           float* __restrict__ y) {
    int g = blockIdx.x, t = threadIdx.x;
    __shared__ float p[64], f1[32];
    p[t] = pooled[g * 64 + t];
    __syncthreads();
    if (t < 32) {
        float a = b1[t];
        #pragma unroll
        for (int k = 0; k < 64; ++k) a += p[k] * w1[k * 32 + t];
        f1[t] = fmaxf(a, 0.f);
    }
    __syncthreads();
    if (t < 2) {
        float a = b2[t];
        #pragma unroll
        for (int k = 0; k < 32; ++k) a += f1[k] * w2[k * 2 + t];
        y[g * 2 + t] = a;
    }
}

extern "C" void kernel_launch(void* const* d_in, const int* in_sizes, int n_in,
                              void* d_out, int out_size, void* d_ws, size_t ws_size,
                              hipStream_t stream) {
    const float* x    = (const float*)d_in[0];
    const int*   ei   = (const int*)d_in[1];
    const float* ea   = (const float*)d_in[2];
    const int*   batch= (const int*)d_in[3];
    const float* W0   = (const float*)d_in[4];
    const float* as0  = (const float*)d_in[5];
    const float* ad0  = (const float*)d_in[6];
    const float* We0  = (const float*)d_in[7];
    const float* ae0  = (const float*)d_in[8];
    const float* b0   = (const float*)d_in[9];
    const float* Wh   = (const float*)d_in[10];
    const float* ash  = (const float*)d_in[11];
    const float* adh  = (const float*)d_in[12];
    const float* Weh  = (const float*)d_in[13];
    const float* aeh  = (const float*)d_in[14];
    const float* bh   = (const float*)d_in[15];
    const float* w1   = (const float*)d_in[16];
    const float* b1   = (const float*)d_in[17];
    const float* w2   = (const float*)d_in[18];
    const float* b2   = (const float*)d_in[19];
    float* out = (float*)d_out;

    char* wsb = (char*)d_ws;
    size_t off = 0;
    auto alloc = [&](size_t bytes) { char* p = wsb + off; off += (bytes + 255) & ~(size_t)255; return p; };
    int*    row_ptr = (int*)alloc((size_t)(N_NODES + 1) * 4);
    float*  ea_csr  = (float*)alloc((size_t)E_SL * EA_STRIDE * 4);
    float*  als     = (float*)alloc((size_t)N_NODES * 4 * 4);
    float*  ald     = (float*)alloc((size_t)N_NODES * 4 * 4);
    float*  weff    = (float*)alloc(3 * 32 * 4);
    float*  pooled  = (float*)alloc((size_t)NUM_GRAPHS * 64 * 4);
    __half* bufA    = (__half*)alloc((size_t)N_NODES * 64 * 2);  // xp (fp16)
    float*  bufB    = (float*)alloc((size_t)N_NODES * 64 * 4);   // h (layer output, fp32)
    // CSR-build scratch ALIASED into bufA (dead before xp_kernel writes bufA)
    int* cnt    = (int*)bufA;
    int* cursor = cnt + N_NODES;     // contiguous with cnt -> single memset
    int* bsum   = cursor + N_NODES;

    // ---- CSR build (once) ----
    hipMemsetAsync(cnt, 0, (size_t)2 * N_NODES * 4, stream);   // cnt + cursor
    hist_kernel<<<(N_EDGES + 255) / 256, 256, 0, stream>>>(ei, cnt);
    scan_local_kernel<<<SCAN_NB, 256, 0, stream>>>(cnt, row_ptr, bsum);
    scan_bsum_kernel<<<1, 64, 0, stream>>>(bsum);
    scan_add_kernel<<<(N_NODES + 256) / 256, 256, 0, stream>>>(row_ptr, bsum);
    build_csr_kernel<<<(int)(((long long)N_EDGES * 8 + 255) / 256), 256, 0, stream>>>(
        ei, ea, row_ptr, cursor, ea_csr);
    mean_ea_kernel<<<(N_NODES * 2 + 255) / 256, 256, 0, stream>>>(row_ptr, ea_csr);
    weff_all_kernel<<<1, 128, 0, stream>>>(We0, ae0, Weh, aeh, weff);

    // ---- 3 GAT layers (xin -> bufA(xp fp16) -> bufB(h); bufB feeds next layer) ----
    for (int layer = 0; layer < 3; ++layer) {
        const float *W, *as_, *ad_, *bb, *xin;
        int relu_flag = (layer == 0);
        if (layer == 0) {
            W = W0; as_ = as0; ad_ = ad0; bb = b0; xin = x;
        } else {
            int i = layer - 1;
            W   = Wh  + (size_t)i * 64 * 64;
            as_ = ash + (size_t)i * 64;
            ad_ = adh + (size_t)i * 64;
            bb  = bh  + (size_t)i * 64;
            xin = bufB;
        }
        int xpgrid = (N_NODES + XP_NODES_PER_BLK - 1) / XP_NODES_PER_BLK;
        if (layer == 0)
            xp_kernel<32><<<xpgrid, 64, 0, stream>>>(xin, W, as_, ad_, bufA, als, ald);
        else
            xp_kernel<64><<<xpgrid, 64, 0, stream>>>(xin, W, as_, ad_, bufA, als, ald);
        gat_node_kernel<<<(N_NODES + 3) / 4, 256, 0, stream>>>(
            row_ptr, ea_csr, als, ald, weff + layer * 32, bufA, bufB, bb, relu_flag);
    }
    pool_kernel<<<NUM_GRAPHS, 256, 0, stream>>>(bufB, batch, pooled);
    mlp_kernel<<<NUM_GRAPHS, 64, 0, stream>>>(pooled, w1, b1, w2, b2, out);
}